// Round 2
// baseline (777.249 us; speedup 1.0000x reference)
//
#include <hip/hip_runtime.h>
#include <hip/hip_bf16.h>

// FastTSAGEConv: E=500000 edges, N=50000 nodes, F_IN=F_OUT=128.
// Device dtypes: float tensors = float32, index tensors = int32, output = float32.
// out[e,:] = dst_feat[e,:]@W_self + b_self + (segcumsum(src)[dst_max_eid[e],:]/(deg[e]+1))@W_neigh + b_neigh
// GEMM runs in bf16 MFMA (inputs converted on the fly); cumsum stored bf16 in ws.

#define FDIM 128
#define NNODES 50000

typedef __attribute__((ext_vector_type(4))) float f32x4;
typedef __attribute__((ext_vector_type(2))) float f32x2;
typedef __attribute__((ext_vector_type(8))) short bf16x8;

static __device__ __forceinline__ float bf2f(unsigned short u) {
  union { unsigned int i; float f; } v; v.i = ((unsigned int)u) << 16; return v.f;
}
static __device__ __forceinline__ unsigned short f2bf(float f) {
  union { float f; unsigned int i; } v; v.f = f;
  unsigned int x = v.i;
  return (unsigned short)((x + 0x7fffu + ((x >> 16) & 1u)) >> 16); // RNE
}

// ---------------------------------------------------------------------------
// Kernel 0: pack [W_self; W_neigh] (256x128 f32) into bf16 MFMA B-fragment
// order. Fragment (ks, n0, lane) = W_comb[ks*32 + (lane>>4)*8 + j][n0*16 + (lane&15)],
// j=0..7, stored contiguously at ((ks*8+n0)*64 + lane)*8 bf16. GEMM B-loads
// become one coalesced dwordx4 per fragment, L2-resident (64 KB total).
// ---------------------------------------------------------------------------
__global__ __launch_bounds__(256) void pack_w_kernel(
    const float* __restrict__ Wself,
    const float* __restrict__ Wneigh,
    unsigned short* __restrict__ Wp)
{
  int t = blockIdx.x * blockDim.x + threadIdx.x; // 0..4095
  if (t >= 8 * 8 * 64) return;
  int l  = t & 63;
  int n0 = (t >> 6) & 7;
  int ks = t >> 9;
  int n = n0 * 16 + (l & 15);
  int kbase = ks * 32 + ((l >> 4) * 8);
  unsigned short outv[8] __attribute__((aligned(16)));
#pragma unroll
  for (int j = 0; j < 8; ++j) {
    int k = kbase + j;
    float w = (k < FDIM) ? Wself[k * FDIM + n] : Wneigh[(k - FDIM) * FDIM + n];
    outv[j] = f2bf(w);
  }
  ((uint4*)Wp)[t] = *(const uint4*)outv;
}

// ---------------------------------------------------------------------------
// Kernel 1: segmented inclusive cumsum of src_feat (f32) over dst segments.
// One wave per dst node: binary-search [start,end), sequential f32 accumulate,
// store bf16 cumsum rows (halves ws traffic). Lane i owns feature cols 2i,2i+1.
// ---------------------------------------------------------------------------
__global__ __launch_bounds__(256) void seg_cumsum_kernel(
    const float* __restrict__ src,            // [E][128] f32
    const int* __restrict__ dst_ids,          // [E] sorted int32
    unsigned short* __restrict__ cs,          // [E][128] bf16 out
    int E, int nnodes)
{
  int wave = (blockIdx.x * blockDim.x + threadIdx.x) >> 6;
  int lane = threadIdx.x & 63;
  if (wave >= nnodes) return;

  // lower bound
  int lo = 0, hi = E;
  while (lo < hi) { int mid = (lo + hi) >> 1; if (dst_ids[mid] < wave) lo = mid + 1; else hi = mid; }
  int start = lo;
  // upper bound
  int lo2 = start, hi2 = E;
  while (lo2 < hi2) { int mid = (lo2 + hi2) >> 1; if (dst_ids[mid] <= wave) lo2 = mid + 1; else hi2 = mid; }
  int end = lo2;

  float a0 = 0.f, a1 = 0.f;
  for (int j = start; j < end; ++j) {
    f32x2 v = *(const f32x2*)(src + (size_t)j * FDIM + lane * 2);
    a0 += v.x;
    a1 += v.y;
    unsigned int w = ((unsigned int)f2bf(a1) << 16) | (unsigned int)f2bf(a0);
    *(unsigned int*)(cs + (size_t)j * FDIM + lane * 2) = w;
  }
}

// ---------------------------------------------------------------------------
// Kernel 2: out = [dst_feat | h_neigh] @ [W_self; W_neigh] + b_self + b_neigh
// Block = 256 thr = 4 waves; 16 edge-rows per wave (64/block).
// mfma_f32_16x16x32_bf16: A[m=lane&15][k=quad*8+j], B[k=quad*8+j][n=lane&15],
// D row=quad*4+reg, col=lane&15. K=256 => 8 k-steps; N=128 => 8 n-tiles.
// A-frags straight from global into regs; B-frags from packed Wp (L2). No LDS.
// ---------------------------------------------------------------------------
__global__ __launch_bounds__(256) void gemm_kernel(
    const float* __restrict__ dstf,            // [E][128] f32
    const unsigned short* __restrict__ cs,     // [E][128] bf16 (cumsum)
    const int* __restrict__ dst_max_eid,       // [E] int32
    const float* __restrict__ dst_deg,         // [E] f32 (integer-valued)
    const unsigned short* __restrict__ Wp,     // packed fragments, 32768 bf16
    const float* __restrict__ b_self,          // [128] f32
    const float* __restrict__ b_neigh,         // [128] f32
    float* __restrict__ out,                   // [E][128] f32
    int E)
{
  int lane = threadIdx.x & 63;
  int wave = threadIdx.x >> 6;
  int quad = lane >> 4;
  int lnib = lane & 15;
  int m0 = blockIdx.x * 64 + wave * 16;
  int row = m0 + lnib;
  int rclamp = (row < E) ? row : (E - 1);

  bf16x8 afrag[8];
  // self half: k in [0,128) — f32 rows converted to bf16
  const float* arow = dstf + (size_t)rclamp * FDIM + quad * 8;
#pragma unroll
  for (int ks = 0; ks < 4; ++ks) {
    f32x4 lo = *(const f32x4*)(arow + ks * 32);
    f32x4 hi = *(const f32x4*)(arow + ks * 32 + 4);
    bf16x8 a;
#pragma unroll
    for (int j = 0; j < 4; ++j) {
      a[j]     = (short)f2bf(lo[j]);
      a[4 + j] = (short)f2bf(hi[j]);
    }
    afrag[ks] = a;
  }

  // neigh half: gather bf16 cumsum row, scale by 1/(deg+1), k in [128,256)
  int eid = dst_max_eid[rclamp];
  float invc = 1.0f / (dst_deg[rclamp] + 1.0f);
  const unsigned short* nrow = cs + (size_t)eid * FDIM + quad * 8;
#pragma unroll
  for (int ks = 0; ks < 4; ++ks) {
    bf16x8 raw = *(const bf16x8*)(nrow + ks * 32);
    bf16x8 sc;
#pragma unroll
    for (int j = 0; j < 8; ++j)
      sc[j] = (short)f2bf(bf2f((unsigned short)raw[j]) * invc);
    afrag[4 + ks] = sc;
  }

  f32x4 acc[8];
#pragma unroll
  for (int n0 = 0; n0 < 8; ++n0) acc[n0] = (f32x4){0.f, 0.f, 0.f, 0.f};

  const bf16x8* wpv = (const bf16x8*)Wp;
#pragma unroll
  for (int ks = 0; ks < 8; ++ks) {
#pragma unroll
    for (int n0 = 0; n0 < 8; ++n0) {
      bf16x8 b = wpv[(ks * 8 + n0) * 64 + lane];
      acc[n0] = __builtin_amdgcn_mfma_f32_16x16x32_bf16(afrag[ks], b, acc[n0], 0, 0, 0);
    }
  }

  // epilogue: lane writes rows m0+quad*4+r, col n0*16+lnib (f32)
#pragma unroll
  for (int n0 = 0; n0 < 8; ++n0) {
    int n = n0 * 16 + lnib;
    float bias = b_self[n] + b_neigh[n];
#pragma unroll
    for (int r = 0; r < 4; ++r) {
      int orow = m0 + quad * 4 + r;
      if (orow < E)
        out[(size_t)orow * FDIM + n] = acc[n0][r] + bias;
    }
  }
}

extern "C" void kernel_launch(void* const* d_in, const int* in_sizes, int n_in,
                              void* d_out, int out_size, void* d_ws, size_t ws_size,
                              hipStream_t stream) {
  const float* src_feat    = (const float*)d_in[0];
  const float* dst_feat    = (const float*)d_in[1];
  const int*   dst_ids     = (const int*)d_in[2];
  const int*   dst_max_eid = (const int*)d_in[3];
  const float* dst_deg     = (const float*)d_in[4];
  const float* W_self      = (const float*)d_in[5];
  const float* b_self      = (const float*)d_in[6];
  const float* W_neigh     = (const float*)d_in[7];
  const float* b_neigh     = (const float*)d_in[8];

  int E = in_sizes[0] / FDIM;

  // ws layout: [0,64KB) packed bf16 W fragments; [64KB, 64KB + E*128*2) bf16 cumsum
  unsigned short* Wp = (unsigned short*)d_ws;
  unsigned short* cs = (unsigned short*)((char*)d_ws + 65536);

  pack_w_kernel<<<16, 256, 0, stream>>>(W_self, W_neigh, Wp);

  int nwaves_blocks = (NNODES * 64 + 255) / 256;
  seg_cumsum_kernel<<<nwaves_blocks, 256, 0, stream>>>(src_feat, dst_ids, cs, E, NNODES);

  int gblocks = (E + 63) / 64;
  gemm_kernel<<<gblocks, 256, 0, stream>>>(dst_feat, cs, dst_max_eid, dst_deg, Wp,
                                           b_self, b_neigh, (float*)d_out, E);
}